// Round 7
// baseline (371.824 us; speedup 1.0000x reference)
//
#include <hip/hip_runtime.h>
#include <hip/hip_bf16.h>
#include <math.h>

#define DIM_  1536
#define NH_   12
#define HD_   128
#define S_    2048
#define B_    2
#define M_    (B_*S_)   /* 4096 rows */

typedef __attribute__((ext_vector_type(8))) _Float16 f16x8;
typedef __attribute__((ext_vector_type(4))) short short4v;
typedef __attribute__((ext_vector_type(8))) short short8v;
typedef __attribute__((ext_vector_type(4))) float f32x4;

#define SSCALE_LOG2E (0.08838834764831845f * 1.4426950408889634f)

static __device__ __forceinline__ short f2h(float f) {
  union { _Float16 h; short s; } u;
  u.h = (_Float16)f;
  return u.s;
}

static __device__ __forceinline__ unsigned pk2h(float a, float b) {
  typedef __attribute__((ext_vector_type(2))) __fp16 fp16x2;
  union { fp16x2 v; unsigned u; } u2;
  u2.v = __builtin_amdgcn_cvt_pkrtz(a, b);
  return u2.u;
}

// ---------------------------------------------------------------------------
// fp32 -> fp16 pack, 8 elems/thread
// ---------------------------------------------------------------------------
__global__ __launch_bounds__(256) void f2h_k(
    const float* __restrict__ in, short* __restrict__ out, int n8)
{
  int i = blockIdx.x * 256 + threadIdx.x;
  if (i >= n8) return;
  const float4* p = (const float4*)in + (size_t)i * 2;
  float4 a = p[0], b = p[1];
  short8v o;
  o[0] = f2h(a.x); o[1] = f2h(a.y); o[2] = f2h(a.z); o[3] = f2h(a.w);
  o[4] = f2h(b.x); o[5] = f2h(b.y); o[6] = f2h(b.z); o[7] = f2h(b.w);
  *((short8v*)out + i) = o;
}

// ---------------------------------------------------------------------------
// MFMA fp16 GEMM core: Out[4096,1536] = A16[4096,1536] @ W[1536,1536]^T + bias
// 128x128 tile, BK=32, 4 waves (2x2). (unchanged from R2)
// ---------------------------------------------------------------------------
static __device__ __forceinline__ void gemm128_core(
    const short* __restrict__ A16, const float* __restrict__ W,
    const float* __restrict__ bias, float* __restrict__ Out,
    int m0, int n0)
{
  __shared__ __align__(16) char Atile[8192];
  __shared__ __align__(16) char Btile[8192];
  const int tid = threadIdx.x;
  const int l  = tid & 63, w = tid >> 6;
  const int wr = w >> 1, wc = w & 1;
  const int lc = l & 15, lg = l >> 4;

  f32x4 acc[4][4] = {};

  for (int k0 = 0; k0 < DIM_; k0 += 32) {
#pragma unroll
    for (int i = 0; i < 2; ++i) {
      int row   = i * 64 + w * 16 + (l >> 2);
      int slot  = l & 3;
      int gslot = slot ^ ((row >> 1) & 3);
      const short* g = A16 + (size_t)(m0 + row) * DIM_ + k0 + gslot * 8;
      __builtin_amdgcn_global_load_lds(
          (const __attribute__((address_space(1))) unsigned*)g,
          (__attribute__((address_space(3))) unsigned*)(Atile + i * 4096 + w * 1024),
          16, 0, 0);
    }
#pragma unroll
    for (int i = 0; i < 4; ++i) {
      int e   = tid + i * 256;
      int row = e >> 3, f4 = e & 7;
      float4 v4 = *(const float4*)(W + (size_t)(n0 + row) * DIM_ + k0 + f4 * 4);
      short4v h4;
      h4[0] = f2h(v4.x); h4[1] = f2h(v4.y); h4[2] = f2h(v4.z); h4[3] = f2h(v4.w);
      int slot = f4 >> 1;
      *(short4v*)(Btile + row * 64 + (((slot ^ ((row >> 1) & 3)) << 4)) + ((f4 & 1) << 3)) = h4;
    }
    __syncthreads();

    f16x8 af[4], bf[4];
#pragma unroll
    for (int mt = 0; mt < 4; ++mt) {
      int ar = wr * 64 + mt * 16 + lc;
      af[mt] = *(const f16x8*)(Atile + ar * 64 + ((lg ^ ((ar >> 1) & 3)) << 4));
    }
#pragma unroll
    for (int nt = 0; nt < 4; ++nt) {
      int br = wc * 64 + nt * 16 + lc;
      bf[nt] = *(const f16x8*)(Btile + br * 64 + ((lg ^ ((br >> 1) & 3)) << 4));
    }
#pragma unroll
    for (int mt = 0; mt < 4; ++mt)
#pragma unroll
      for (int nt = 0; nt < 4; ++nt)
        acc[mt][nt] = __builtin_amdgcn_mfma_f32_16x16x32_f16(af[mt], bf[nt], acc[mt][nt], 0, 0, 0);
    __syncthreads();
  }

#pragma unroll
  for (int nt = 0; nt < 4; ++nt) {
    int col = n0 + wc * 64 + nt * 16 + lc;
    float bb = bias[col];
#pragma unroll
    for (int mt = 0; mt < 4; ++mt) {
#pragma unroll
      for (int r = 0; r < 4; ++r) {
        int rowm = m0 + wr * 64 + mt * 16 + lg * 4 + r;
        Out[(size_t)rowm * DIM_ + col] = acc[mt][nt][r] + bb;
      }
    }
  }
}

__global__ __launch_bounds__(256) void gemm_qkv_k(
    const short* __restrict__ x16,
    const float* __restrict__ wq, const float* __restrict__ wk, const float* __restrict__ wv,
    const float* __restrict__ bq, const float* __restrict__ bk, const float* __restrict__ bv,
    float* __restrict__ qf, float* __restrict__ kf, float* __restrict__ vf)
{
  const int z = blockIdx.z;
  const float* W  = (z == 0) ? wq : (z == 1) ? wk : wv;
  const float* bi = (z == 0) ? bq : (z == 1) ? bk : bv;
  float*       O  = (z == 0) ? qf : (z == 1) ? kf : vf;
  gemm128_core(x16, W, bi, O, blockIdx.y * 128, blockIdx.x * 128);
}

__global__ __launch_bounds__(256) void gemm_out_k(
    const short* __restrict__ att16, const float* __restrict__ wo,
    const float* __restrict__ bo, float* __restrict__ out)
{
  gemm128_core(att16, wo, bo, out, blockIdx.y * 128, blockIdx.x * 128);
}

// ---------------------------------------------------------------------------
// RMSNorm + grid RoPE -> fp16 head-major [b][h][s][d], with output scale
// folded in (qsc = sscale*log2e for Q, 1.0 for K).
// ---------------------------------------------------------------------------
__global__ __launch_bounds__(256) void rms_rope_pack_k(
    const float* __restrict__ t, const float* __restrict__ w,
    const float* __restrict__ cf, const float* __restrict__ sf,
    const float* __restrict__ ch, const float* __restrict__ sh,
    const float* __restrict__ cw, const float* __restrict__ sw,
    short* __restrict__ outb, float qsc)
{
  const int row = blockIdx.x;
  const int b   = row >> 11;
  const int s   = row & (S_ - 1);
  const float* rp = t + (size_t)row * DIM_;

  float ss = 0.f;
  for (int i = threadIdx.x; i < DIM_; i += 256) { float v2 = rp[i]; ss += v2 * v2; }
#pragma unroll
  for (int off = 32; off > 0; off >>= 1) ss += __shfl_down(ss, off);
  __shared__ float red[4];
  if ((threadIdx.x & 63) == 0) red[threadIdx.x >> 6] = ss;
  __syncthreads();
  float scale = rsqrtf((red[0] + red[1] + red[2] + red[3]) * (1.f / DIM_) + 1e-6f) * qsc;

  const int fi = s >> 8;
  const int hi = (s >> 4) & 15;
  const int wi = s & 15;

  for (int p = threadIdx.x; p < NH_ * 64; p += 256) {
    int n = p >> 6, c = p & 63;
    float co, si;
    if (c < 22)      { co = cf[fi * 22 + c];        si = sf[fi * 22 + c]; }
    else if (c < 43) { co = ch[hi * 21 + (c - 22)]; si = sh[hi * 21 + (c - 22)]; }
    else             { co = cw[wi * 21 + (c - 43)]; si = sw[wi * 21 + (c - 43)]; }
    int d0 = n * HD_ + 2 * c;
    float xr = rp[d0]     * scale * w[d0];
    float xi = rp[d0 + 1] * scale * w[d0 + 1];
    float rr = xr * co - xi * si;
    float ri = xr * si + xi * co;
    *(unsigned int*)(outb + (((size_t)(b * NH_ + n) * S_ + s) * HD_ + 2 * c)) = pk2h(rr, ri);
  }
}

// ---------------------------------------------------------------------------
// V transpose: fp32 [b*S+s][h*128+d] -> fp16 [b][h][d][s]. (unchanged)
// ---------------------------------------------------------------------------
__global__ __launch_bounds__(256) void v_transpose_k(
    const float* __restrict__ v, short* __restrict__ vtb)
{
  const int bh = blockIdx.y;
  const int b  = bh / NH_;
  const int h  = bh - b * NH_;
  const int s0 = blockIdx.x << 6;
  __shared__ short tile[64][130];
  const int tid = threadIdx.x;
#pragma unroll
  for (int i = 0; i < 8; ++i) {
    int f  = tid + (i << 8);
    int sl = f >> 5, d4 = f & 31;
    float4 t4 = *(const float4*)(v + (size_t)(b * S_ + s0 + sl) * DIM_ + h * 128 + d4 * 4);
    tile[sl][d4 * 4 + 0] = f2h(t4.x);
    tile[sl][d4 * 4 + 1] = f2h(t4.y);
    tile[sl][d4 * 4 + 2] = f2h(t4.z);
    tile[sl][d4 * 4 + 3] = f2h(t4.w);
  }
  __syncthreads();
#pragma unroll
  for (int i = 0; i < 8; ++i) {
    int f  = tid + (i << 8);
    int d  = f >> 4, s4 = f & 15;
    short4v o4;
    o4[0] = tile[s4 * 4 + 0][d];
    o4[1] = tile[s4 * 4 + 1][d];
    o4[2] = tile[s4 * 4 + 2][d];
    o4[3] = tile[s4 * 4 + 3][d];
    *(short4v*)(vtb + ((size_t)bh * HD_ + d) * S_ + s0 + s4 * 4) = o4;
  }
}

// ---------------------------------------------------------------------------
// fp16 MFMA flash attention v4: barrier-free, direct-global fragments.
// Block = 2 independent waves x 32 queries (no __syncthreads at all).
// K and V^T are L2-resident (25 MB total); MFMA fragments are read directly
// from global per wave. Only P round-trips through per-wave private LDS.
// Q is pre-scaled by sscale*log2e at pack time, so QK output is already in
// the log2 domain.
//   QK:  mfma(A=Kfrag, B=Qfrag) -> S^T: col=lc=query, row=4lg+r=key
//   PV:  mfma(A=Pfrag, B=Vfrag) -> O: col=lc=d, row=4lg+r=query
// ---------------------------------------------------------------------------
__global__ __launch_bounds__(128, 2) void attn_mfma4_k(
    const short* __restrict__ qb, const short* __restrict__ kb,
    const short* __restrict__ vtb, const int* __restrict__ seq_lens,
    short* __restrict__ o16)
{
  const int bh = blockIdx.y;
  const int b  = bh / NH_;
  const int h  = bh - b * NH_;
  const int q0 = blockIdx.x << 6;       // 64 queries per block
  const int kvlen = seq_lens[b];
  const int tid  = threadIdx.x;
  const int wid  = tid >> 6;            // 0..1
  const int lane = tid & 63;
  const int lg   = lane >> 4;           // 0..3
  const int lc   = lane & 15;
  const int xo   = (lc & 7) << 4;

  __shared__ __align__(16) char Pt[2][4096];   // per-wave [32 q][64 k] swizzled

  // ---- Q hoist (B-frag: col=lc=query, k=lg*8+i=d), two 16-q halves per wave
  f16x8 bq0[4], bq1[4];
  {
    const size_t base0 = ((size_t)bh * S_ + q0 + wid * 32 + lc) * HD_;
#pragma unroll
    for (int dc = 0; dc < 4; ++dc) {
      bq0[dc] = *(const f16x8*)(qb + base0 + dc * 32 + lg * 8);
      bq1[dc] = *(const f16x8*)(qb + base0 + 16 * HD_ + dc * 32 + lg * 8);
    }
  }

  // per-lane fragment base pointers
  const short* kfp = kb  + ((size_t)bh * S_  + lc) * HD_ + lg * 8;  // + key*HD_ + dc*32
  const short* vfp = vtb + ((size_t)bh * HD_ + lc) * S_  + lg * 8;  // + n*16*S_ + k0 + kc*32

  f32x4 oacc0[8] = {}, oacc1[8] = {};
  float m0 = -3.0e38f, m1 = -3.0e38f, l0 = 0.f, l1 = 0.f;

  const int nt = kvlen >> 6;
  for (int ti = 0; ti < nt; ++ti) {
    const int k0 = ti << 6;
    const short* kp = kfp + (size_t)k0 * HD_;
    const short* vp = vfp + k0;

    // ---- QK^T (swapped): S^T[key][q], direct-global K fragments
    f32x4 s0[4], s1[4];
#pragma unroll
    for (int kt = 0; kt < 4; ++kt) {
      f32x4 a0 = {0.f, 0.f, 0.f, 0.f}, a1 = {0.f, 0.f, 0.f, 0.f};
      const short* kr = kp + kt * 16 * HD_;
#pragma unroll
      for (int dc = 0; dc < 4; ++dc) {
        f16x8 kf = *(const f16x8*)(kr + dc * 32);
        a0 = __builtin_amdgcn_mfma_f32_16x16x32_f16(kf, bq0[dc], a0, 0, 0, 0);
        a1 = __builtin_amdgcn_mfma_f32_16x16x32_f16(kf, bq1[dc], a1, 0, 0, 0);
      }
      s0[kt] = a0; s1[kt] = a1;
    }

    // ---- prefetch V kc=0 half (lands during softmax)
    f16x8 vpre[8];
#pragma unroll
    for (int n = 0; n < 8; ++n) vpre[n] = *(const f16x8*)(vp + n * 16 * S_);

    // ---- softmax (lane holds 16 keys for query lc / 16+lc), log2 domain
    float t0 = -3.0e38f, t1 = -3.0e38f;
#pragma unroll
    for (int kt = 0; kt < 4; ++kt)
#pragma unroll
      for (int r = 0; r < 4; ++r) {
        t0 = fmaxf(t0, s0[kt][r]); t1 = fmaxf(t1, s1[kt][r]);
      }
    t0 = fmaxf(t0, __shfl_xor(t0, 16)); t0 = fmaxf(t0, __shfl_xor(t0, 32));
    t1 = fmaxf(t1, __shfl_xor(t1, 16)); t1 = fmaxf(t1, __shfl_xor(t1, 32));

    if (__any((t0 > m0 + 8.f) || (t1 > m1 + 8.f))) {   // defer-max rescale
      float mn0 = fmaxf(m0, t0), mn1 = fmaxf(m1, t1);
      float a0 = exp2f(m0 - mn0), a1 = exp2f(m1 - mn1);
      m0 = mn0; m1 = mn1; l0 *= a0; l1 *= a1;
#pragma unroll
      for (int r = 0; r < 4; ++r) {
        float ar0 = __shfl(a0, 4 * lg + r);
        float ar1 = __shfl(a1, 4 * lg + r);
#pragma unroll
        for (int n = 0; n < 8; ++n) { oacc0[n][r] *= ar0; oacc1[n][r] *= ar1; }
      }
    }
    float ls0 = 0.f, ls1 = 0.f;
#pragma unroll
    for (int kt = 0; kt < 4; ++kt)
#pragma unroll
      for (int r = 0; r < 4; ++r) {
        float p0 = exp2f(s0[kt][r] - m0); s0[kt][r] = p0; ls0 += p0;
        float p1 = exp2f(s1[kt][r] - m1); s1[kt][r] = p1; ls1 += p1;
      }
    ls0 += __shfl_xor(ls0, 16); ls0 += __shfl_xor(ls0, 32); l0 += ls0;
    ls1 += __shfl_xor(ls1, 16); ls1 += __shfl_xor(ls1, 32); l1 += ls1;

    // ---- P -> LDS (packed u32 pairs via v_cvt_pkrtz, swizzled)
    {
      char* pr0 = Pt[wid] + lc * 128;
      char* pr1 = Pt[wid] + (16 + lc) * 128;
#pragma unroll
      for (int kt = 0; kt < 4; ++kt) {
#pragma unroll
        for (int rr = 0; rr < 2; ++rr) {
          unsigned u0 = pk2h(s0[kt][2 * rr], s0[kt][2 * rr + 1]);
          unsigned u1 = pk2h(s1[kt][2 * rr], s1[kt][2 * rr + 1]);
          int off = (kt * 32 + lg * 8 + rr * 4) ^ xo;
          *(unsigned*)(pr0 + off) = u0;
          *(unsigned*)(pr1 + off) = u1;
        }
      }
    }
    asm volatile("s_waitcnt lgkmcnt(0)" ::: "memory");
    __builtin_amdgcn_sched_barrier(0);

    // ---- PV: O += P @ V  (kc=0 from prefetch regs, kc=1 direct-global)
#pragma unroll
    for (int kc = 0; kc < 2; ++kc) {
      f16x8 pa0 = *(const f16x8*)(Pt[wid] + lc * 128 + ((kc * 64 + lg * 16) ^ xo));
      f16x8 pa1 = *(const f16x8*)(Pt[wid] + (16 + lc) * 128 + ((kc * 64 + lg * 16) ^ xo));
#pragma unroll
      for (int n = 0; n < 8; ++n) {
        f16x8 vf = kc ? *(const f16x8*)(vp + n * 16 * S_ + 32) : vpre[n];
        oacc0[n] = __builtin_amdgcn_mfma_f32_16x16x32_f16(pa0, vf, oacc0[n], 0, 0, 0);
        oacc1[n] = __builtin_amdgcn_mfma_f32_16x16x32_f16(pa1, vf, oacc1[n], 0, 0, 0);
      }
    }
  }

  // ---- epilogue: O row=query=4lg+r, col=d=n*16+lc
#pragma unroll
  for (int r = 0; r < 4; ++r) {
    float li0 = 1.f / __shfl(l0, 4 * lg + r);
    float li1 = 1.f / __shfl(l1, 4 * lg + r);
    int qrow0 = q0 + wid * 32 + 4 * lg + r;
#pragma unroll
    for (int n = 0; n < 8; ++n) {
      o16[((size_t)(b * S_ + qrow0) * NH_ + h) * HD_ + n * 16 + lc] = f2h(oacc0[n][r] * li0);
      o16[((size_t)(b * S_ + qrow0 + 16) * NH_ + h) * HD_ + n * 16 + lc] = f2h(oacc1[n][r] * li1);
    }
  }
}

// ---------------------------------------------------------------------------
extern "C" void kernel_launch(void* const* d_in, const int* in_sizes, int n_in,
                              void* d_out, int out_size, void* d_ws, size_t ws_size,
                              hipStream_t stream) {
  const float* x        = (const float*)d_in[0];
  const int*   seq_lens = (const int*)d_in[1];
  const float* wq = (const float*)d_in[5];
  const float* bq = (const float*)d_in[6];
  const float* wk = (const float*)d_in[7];
  const float* bk = (const float*)d_in[8];
  const float* wv = (const float*)d_in[9];
  const float* bv = (const float*)d_in[10];
  const float* wo = (const float*)d_in[11];
  const float* bo = (const float*)d_in[12];
  const float* nq = (const float*)d_in[13];
  const float* nk = (const float*)d_in[14];
  const float* cf = (const float*)d_in[15];
  const float* sf = (const float*)d_in[16];
  const float* ch = (const float*)d_in[17];
  const float* sh = (const float*)d_in[18];
  const float* cw = (const float*)d_in[19];
  const float* sw = (const float*)d_in[20];

  const size_t rowelems = (size_t)M_ * DIM_;          // 6291456
  float* qf  = (float*)d_ws;
  float* kf  = qf + rowelems;
  float* vf  = kf + rowelems;
  short* x16 = (short*)(vf + rowelems);
  short* vt  = x16;                       // reuse after GEMMs
  short* qh  = (short*)vf;                // reuse after v_transpose
  short* kh  = qh + rowelems;
  short* att16 = (short*)qf;              // reuse after rms_rope(q)
  float* out = (float*)d_out;

  f2h_k<<<(int)(rowelems / 8 / 256), 256, 0, stream>>>(x, x16, (int)(rowelems / 8));

  gemm_qkv_k<<<dim3(DIM_ / 128, M_ / 128, 3), 256, 0, stream>>>(
      x16, wq, wk, wv, bq, bk, bv, qf, kf, vf);

  v_transpose_k<<<dim3(S_ / 64, B_ * NH_), 256, 0, stream>>>(vf, vt);

  rms_rope_pack_k<<<M_, 256, 0, stream>>>(qf, nq, cf, sf, ch, sh, cw, sw, qh,
                                          SSCALE_LOG2E);
  rms_rope_pack_k<<<M_, 256, 0, stream>>>(kf, nk, cf, sf, ch, sh, cw, sw, kh, 1.0f);

  attn_mfma4_k<<<dim3(S_ / 64, B_ * NH_), 128, 0, stream>>>(qh, kh, vt, seq_lens, att16);

  gemm_out_k<<<dim3(DIM_ / 128, M_ / 128), 256, 0, stream>>>(att16, wo, bo, out);
}

// Round 8
// 269.014 us; speedup vs baseline: 1.3822x; 1.3822x over previous
//
#include <hip/hip_runtime.h>
#include <hip/hip_bf16.h>
#include <math.h>

#define DIM_  1536
#define NH_   12
#define HD_   128
#define S_    2048
#define B_    2
#define M_    (B_*S_)   /* 4096 rows */

typedef __attribute__((ext_vector_type(8))) _Float16 f16x8;
typedef __attribute__((ext_vector_type(4))) short short4v;
typedef __attribute__((ext_vector_type(8))) short short8v;
typedef __attribute__((ext_vector_type(4))) float f32x4;

#define SSCALE_LOG2E (0.08838834764831845f * 1.4426950408889634f)

static __device__ __forceinline__ short f2h(float f) {
  union { _Float16 h; short s; } u;
  u.h = (_Float16)f;
  return u.s;
}

static __device__ __forceinline__ unsigned pk2h(float a, float b) {
  typedef __attribute__((ext_vector_type(2))) __fp16 fp16x2;
  union { fp16x2 v; unsigned u; } u2;
  u2.v = __builtin_amdgcn_cvt_pkrtz(a, b);
  return u2.u;
}

// ---------------------------------------------------------------------------
// fp32 -> fp16 pack, 8 elems/thread
// ---------------------------------------------------------------------------
__global__ __launch_bounds__(256) void f2h_k(
    const float* __restrict__ in, short* __restrict__ out, int n8)
{
  int i = blockIdx.x * 256 + threadIdx.x;
  if (i >= n8) return;
  const float4* p = (const float4*)in + (size_t)i * 2;
  float4 a = p[0], b = p[1];
  short8v o;
  o[0] = f2h(a.x); o[1] = f2h(a.y); o[2] = f2h(a.z); o[3] = f2h(a.w);
  o[4] = f2h(b.x); o[5] = f2h(b.y); o[6] = f2h(b.z); o[7] = f2h(b.w);
  *((short8v*)out + i) = o;
}

// ---------------------------------------------------------------------------
// MFMA fp16 GEMM core: Out[4096,1536] = A16[4096,1536] @ W[1536,1536]^T + bias
// 128x128 tile, BK=32, 4 waves (2x2). (unchanged from R2)
// ---------------------------------------------------------------------------
static __device__ __forceinline__ void gemm128_core(
    const short* __restrict__ A16, const float* __restrict__ W,
    const float* __restrict__ bias, float* __restrict__ Out,
    int m0, int n0)
{
  __shared__ __align__(16) char Atile[8192];
  __shared__ __align__(16) char Btile[8192];
  const int tid = threadIdx.x;
  const int l  = tid & 63, w = tid >> 6;
  const int wr = w >> 1, wc = w & 1;
  const int lc = l & 15, lg = l >> 4;

  f32x4 acc[4][4] = {};

  for (int k0 = 0; k0 < DIM_; k0 += 32) {
#pragma unroll
    for (int i = 0; i < 2; ++i) {
      int row   = i * 64 + w * 16 + (l >> 2);
      int slot  = l & 3;
      int gslot = slot ^ ((row >> 1) & 3);
      const short* g = A16 + (size_t)(m0 + row) * DIM_ + k0 + gslot * 8;
      __builtin_amdgcn_global_load_lds(
          (const __attribute__((address_space(1))) unsigned*)g,
          (__attribute__((address_space(3))) unsigned*)(Atile + i * 4096 + w * 1024),
          16, 0, 0);
    }
#pragma unroll
    for (int i = 0; i < 4; ++i) {
      int e   = tid + i * 256;
      int row = e >> 3, f4 = e & 7;
      float4 v4 = *(const float4*)(W + (size_t)(n0 + row) * DIM_ + k0 + f4 * 4);
      short4v h4;
      h4[0] = f2h(v4.x); h4[1] = f2h(v4.y); h4[2] = f2h(v4.z); h4[3] = f2h(v4.w);
      int slot = f4 >> 1;
      *(short4v*)(Btile + row * 64 + (((slot ^ ((row >> 1) & 3)) << 4)) + ((f4 & 1) << 3)) = h4;
    }
    __syncthreads();

    f16x8 af[4], bf[4];
#pragma unroll
    for (int mt = 0; mt < 4; ++mt) {
      int ar = wr * 64 + mt * 16 + lc;
      af[mt] = *(const f16x8*)(Atile + ar * 64 + ((lg ^ ((ar >> 1) & 3)) << 4));
    }
#pragma unroll
    for (int nt = 0; nt < 4; ++nt) {
      int br = wc * 64 + nt * 16 + lc;
      bf[nt] = *(const f16x8*)(Btile + br * 64 + ((lg ^ ((br >> 1) & 3)) << 4));
    }
#pragma unroll
    for (int mt = 0; mt < 4; ++mt)
#pragma unroll
      for (int nt = 0; nt < 4; ++nt)
        acc[mt][nt] = __builtin_amdgcn_mfma_f32_16x16x32_f16(af[mt], bf[nt], acc[mt][nt], 0, 0, 0);
    __syncthreads();
  }

#pragma unroll
  for (int nt = 0; nt < 4; ++nt) {
    int col = n0 + wc * 64 + nt * 16 + lc;
    float bb = bias[col];
#pragma unroll
    for (int mt = 0; mt < 4; ++mt) {
#pragma unroll
      for (int r = 0; r < 4; ++r) {
        int rowm = m0 + wr * 64 + mt * 16 + lg * 4 + r;
        Out[(size_t)rowm * DIM_ + col] = acc[mt][nt][r] + bb;
      }
    }
  }
}

__global__ __launch_bounds__(256) void gemm_qkv_k(
    const short* __restrict__ x16,
    const float* __restrict__ wq, const float* __restrict__ wk, const float* __restrict__ wv,
    const float* __restrict__ bq, const float* __restrict__ bk, const float* __restrict__ bv,
    float* __restrict__ qf, float* __restrict__ kf, float* __restrict__ vf)
{
  const int z = blockIdx.z;
  const float* W  = (z == 0) ? wq : (z == 1) ? wk : wv;
  const float* bi = (z == 0) ? bq : (z == 1) ? bk : bv;
  float*       O  = (z == 0) ? qf : (z == 1) ? kf : vf;
  gemm128_core(x16, W, bi, O, blockIdx.y * 128, blockIdx.x * 128);
}

__global__ __launch_bounds__(256) void gemm_out_k(
    const short* __restrict__ att16, const float* __restrict__ wo,
    const float* __restrict__ bo, float* __restrict__ out)
{
  gemm128_core(att16, wo, bo, out, blockIdx.y * 128, blockIdx.x * 128);
}

// ---------------------------------------------------------------------------
// RMSNorm + grid RoPE -> fp16 head-major [b][h][s][d], with output scale
// folded in (qsc = sscale*log2e for Q, 1.0 for K).
// ---------------------------------------------------------------------------
__global__ __launch_bounds__(256) void rms_rope_pack_k(
    const float* __restrict__ t, const float* __restrict__ w,
    const float* __restrict__ cf, const float* __restrict__ sf,
    const float* __restrict__ ch, const float* __restrict__ sh,
    const float* __restrict__ cw, const float* __restrict__ sw,
    short* __restrict__ outb, float qsc)
{
  const int row = blockIdx.x;
  const int b   = row >> 11;
  const int s   = row & (S_ - 1);
  const float* rp = t + (size_t)row * DIM_;

  float ss = 0.f;
  for (int i = threadIdx.x; i < DIM_; i += 256) { float v2 = rp[i]; ss += v2 * v2; }
#pragma unroll
  for (int off = 32; off > 0; off >>= 1) ss += __shfl_down(ss, off);
  __shared__ float red[4];
  if ((threadIdx.x & 63) == 0) red[threadIdx.x >> 6] = ss;
  __syncthreads();
  float scale = rsqrtf((red[0] + red[1] + red[2] + red[3]) * (1.f / DIM_) + 1e-6f) * qsc;

  const int fi = s >> 8;
  const int hi = (s >> 4) & 15;
  const int wi = s & 15;

  for (int p = threadIdx.x; p < NH_ * 64; p += 256) {
    int n = p >> 6, c = p & 63;
    float co, si;
    if (c < 22)      { co = cf[fi * 22 + c];        si = sf[fi * 22 + c]; }
    else if (c < 43) { co = ch[hi * 21 + (c - 22)]; si = sh[hi * 21 + (c - 22)]; }
    else             { co = cw[wi * 21 + (c - 43)]; si = sw[wi * 21 + (c - 43)]; }
    int d0 = n * HD_ + 2 * c;
    float xr = rp[d0]     * scale * w[d0];
    float xi = rp[d0 + 1] * scale * w[d0 + 1];
    float rr = xr * co - xi * si;
    float ri = xr * si + xi * co;
    *(unsigned int*)(outb + (((size_t)(b * NH_ + n) * S_ + s) * HD_ + 2 * c)) = pk2h(rr, ri);
  }
}

// ---------------------------------------------------------------------------
// V transpose: fp32 [b*S+s][h*128+d] -> fp16 [b][h][d][s]. (unchanged)
// ---------------------------------------------------------------------------
__global__ __launch_bounds__(256) void v_transpose_k(
    const float* __restrict__ v, short* __restrict__ vtb)
{
  const int bh = blockIdx.y;
  const int b  = bh / NH_;
  const int h  = bh - b * NH_;
  const int s0 = blockIdx.x << 6;
  __shared__ short tile[64][130];
  const int tid = threadIdx.x;
#pragma unroll
  for (int i = 0; i < 8; ++i) {
    int f  = tid + (i << 8);
    int sl = f >> 5, d4 = f & 31;
    float4 t4 = *(const float4*)(v + (size_t)(b * S_ + s0 + sl) * DIM_ + h * 128 + d4 * 4);
    tile[sl][d4 * 4 + 0] = f2h(t4.x);
    tile[sl][d4 * 4 + 1] = f2h(t4.y);
    tile[sl][d4 * 4 + 2] = f2h(t4.z);
    tile[sl][d4 * 4 + 3] = f2h(t4.w);
  }
  __syncthreads();
#pragma unroll
  for (int i = 0; i < 8; ++i) {
    int f  = tid + (i << 8);
    int d  = f >> 4, s4 = f & 15;
    short4v o4;
    o4[0] = tile[s4 * 4 + 0][d];
    o4[1] = tile[s4 * 4 + 1][d];
    o4[2] = tile[s4 * 4 + 2][d];
    o4[3] = tile[s4 * 4 + 3][d];
    *(short4v*)(vtb + ((size_t)bh * HD_ + d) * S_ + s0 + s4 * 4) = o4;
  }
}

// ---------------------------------------------------------------------------
// fp16 MFMA flash attention v5: 4 waves x 16 queries, LDS-shared K/V,
// split-barrier pipeline (V staged during QK+softmax, K(t+1) during PV),
// in-lane log2-domain softmax (Q pre-scaled), defer-max, hoisted
// pre-swizzled global_load_lds staging.
//   QK:  mfma(A=Kfrag, B=Qfrag) -> S^T: col=lc=query, row=4lg+r=key
//   PV:  mfma(A=Pfrag, B=Vfrag) -> O: col=lc=d, row=4lg+r=query
// ---------------------------------------------------------------------------
__global__ __launch_bounds__(256) void attn_mfma5_k(
    const short* __restrict__ qb, const short* __restrict__ kb,
    const short* __restrict__ vtb, const int* __restrict__ seq_lens,
    short* __restrict__ o16)
{
  const int bh = blockIdx.y;
  const int b  = bh / NH_;
  const int h  = bh - b * NH_;
  const int q0 = blockIdx.x << 6;       // 64 queries per block
  const int kvlen = seq_lens[b];
  const int tid  = threadIdx.x;
  const int wid  = tid >> 6;            // 0..3
  const int lane = tid & 63;
  const int lg   = lane >> 4;           // 0..3
  const int lc   = lane & 15;
  const int xo   = (lc & 7) << 4;       // fragment-read swizzle (row&7==lc&7)

  __shared__ __align__(16) char Kt[16384];     // [64 keys][256 B] swizzled
  __shared__ __align__(16) char Vt[16384];     // [128 d][128 B] swizzled
  __shared__ __align__(16) char Pt[4][2048];   // per-wave [16 q][128 B] swizzled

  // ---- Q hoist (B-frag: col=lc=query, k=lg*8+i=d); wave owns q0+wid*16..+15
  f16x8 bq[4];
  {
    const size_t base = ((size_t)bh * S_ + q0 + wid * 16 + lc) * HD_;
#pragma unroll
    for (int dc = 0; dc < 4; ++dc)
      bq[dc] = *(const f16x8*)(qb + base + dc * 32 + lg * 8);
  }

  // ---- hoisted pre-swizzled staging pointers
  // K rows per wave: wid*16 + j*4 + lg (j=0..3); row&7 = lg + 4*(j&1)
  const short* kgA = kb + ((size_t)bh * S_ + wid * 16 + lg) * HD_
                        + ((lc * 8) ^ (lg << 3));                       // j even
  const short* kgB = kb + ((size_t)bh * S_ + wid * 16 + 4 + lg) * HD_
                        + ((lc * 8) ^ ((lg ^ 4) << 3));                 // j odd
  // V rows per wave: wid*32 + j*8 + (lane>>3) (j=0..3); row&7 = lane>>3
  const short* vg  = vtb + ((size_t)bh * HD_ + wid * 32 + (lane >> 3)) * S_
                         + (((lane & 7) * 8) ^ ((lane >> 3) << 3));

#define STAGE_K()                                                              \
  {                                                                            \
    _Pragma("unroll")                                                          \
    for (int j = 0; j < 4; ++j) {                                              \
      const short* g = (j & 1) ? (kgB + ((j - 1) >> 1) * (8 * HD_))            \
                               : (kgA + (j >> 1) * (8 * HD_));                 \
      __builtin_amdgcn_global_load_lds(                                        \
          (const __attribute__((address_space(1))) unsigned*)g,                \
          (__attribute__((address_space(3))) unsigned*)(Kt + (wid * 16 + j * 4) * 256), \
          16, 0, 0);                                                           \
    }                                                                          \
  }
#define STAGE_V()                                                              \
  {                                                                            \
    _Pragma("unroll")                                                          \
    for (int j = 0; j < 4; ++j) {                                              \
      __builtin_amdgcn_global_load_lds(                                        \
          (const __attribute__((address_space(1))) unsigned*)(vg + j * 8 * S_),\
          (__attribute__((address_space(3))) unsigned*)(Vt + (wid * 32 + j * 8) * 128), \
          16, 0, 0);                                                           \
    }                                                                          \
  }

  f32x4 oacc[8] = {};
  float m = -3.0e38f, l = 0.f;

  const int nt = kvlen >> 6;

  // ---- prologue: stage K(0)
  STAGE_K();
  kgA += 64 * HD_; kgB += 64 * HD_;
  __syncthreads();                 // K(0) ready

  for (int ti = 0; ti < nt; ++ti) {
    // ---- issue V(ti) loads (land during QK+softmax)
    STAGE_V();
    vg += 64;

    // ---- QK^T (swapped): S^T[key][q] from Kt
    f32x4 s[4];
    __builtin_amdgcn_s_setprio(1);
#pragma unroll
    for (int kt = 0; kt < 4; ++kt) {
      f32x4 a = {0.f, 0.f, 0.f, 0.f};
      const char* kr = Kt + (kt * 16 + lc) * 256;
#pragma unroll
      for (int dc = 0; dc < 4; ++dc) {
        f16x8 kf = *(const f16x8*)(kr + ((dc * 64 + lg * 16) ^ xo));
        a = __builtin_amdgcn_mfma_f32_16x16x32_f16(kf, bq[dc], a, 0, 0, 0);
      }
      s[kt] = a;
    }
    __builtin_amdgcn_s_setprio(0);

    // ---- softmax (lane holds 16 keys for query lc), log2 domain
    float t0 = -3.0e38f;
#pragma unroll
    for (int kt = 0; kt < 4; ++kt)
#pragma unroll
      for (int r = 0; r < 4; ++r) t0 = fmaxf(t0, s[kt][r]);
    t0 = fmaxf(t0, __shfl_xor(t0, 16));
    t0 = fmaxf(t0, __shfl_xor(t0, 32));

    if (__any(t0 > m + 8.f)) {    // defer-max rescale
      float mn = fmaxf(m, t0);
      float a  = exp2f(m - mn);
      m = mn; l *= a;
#pragma unroll
      for (int r = 0; r < 4; ++r) {
        float ar = __shfl(a, 4 * lg + r);
#pragma unroll
        for (int n = 0; n < 8; ++n) oacc[n][r] *= ar;
      }
    }
    float ls = 0.f;
#pragma unroll
    for (int kt = 0; kt < 4; ++kt)
#pragma unroll
      for (int r = 0; r < 4; ++r) {
        float p = exp2f(s[kt][r] - m); s[kt][r] = p; ls += p;
      }
    ls += __shfl_xor(ls, 16);
    ls += __shfl_xor(ls, 32);
    l += ls;

    // ---- P -> LDS (packed u32 pairs via v_cvt_pkrtz, swizzled)
    {
      char* pr = Pt[wid] + lc * 128;
#pragma unroll
      for (int kt = 0; kt < 4; ++kt) {
#pragma unroll
        for (int rr = 0; rr < 2; ++rr) {
          unsigned u = pk2h(s[kt][2 * rr], s[kt][2 * rr + 1]);
          int off = (kt * 32 + lg * 8 + rr * 4) ^ xo;
          *(unsigned*)(pr + off) = u;
        }
      }
    }

    __syncthreads();               // V(ti) ready (vmcnt+lgkm drain); Kt reads done

    // ---- issue K(ti+1) loads (land during PV)
    if (ti + 1 < nt) {
      STAGE_K();
      kgA += 64 * HD_; kgB += 64 * HD_;
    }

    // ---- PV: O += P @ V
    __builtin_amdgcn_s_setprio(1);
#pragma unroll
    for (int kc = 0; kc < 2; ++kc) {
      f16x8 pa = *(const f16x8*)(Pt[wid] + lc * 128 + ((kc * 64 + lg * 16) ^ xo));
#pragma unroll
      for (int n = 0; n < 8; ++n) {
        f16x8 vf = *(const f16x8*)(Vt + (n * 16 + lc) * 128 + ((kc * 64 + lg * 16) ^ xo));
        oacc[n] = __builtin_amdgcn_mfma_f32_16x16x32_f16(pa, vf, oacc[n], 0, 0, 0);
      }
    }
    __builtin_amdgcn_s_setprio(0);

    __syncthreads();               // K(ti+1) ready; Vt reads done
  }

  // ---- epilogue: O row=query=4lg+r, col=d=n*16+lc
#pragma unroll
  for (int r = 0; r < 4; ++r) {
    float li = 1.f / __shfl(l, 4 * lg + r);
    int qrow = q0 + wid * 16 + 4 * lg + r;
#pragma unroll
    for (int n = 0; n < 8; ++n)
      o16[((size_t)(b * S_ + qrow) * NH_ + h) * HD_ + n * 16 + lc] = f2h(oacc[n][r] * li);
  }
#undef STAGE_K
#undef STAGE_V
}

// ---------------------------------------------------------------------------
extern "C" void kernel_launch(void* const* d_in, const int* in_sizes, int n_in,
                              void* d_out, int out_size, void* d_ws, size_t ws_size,
                              hipStream_t stream) {
  const float* x        = (const float*)d_in[0];
  const int*   seq_lens = (const int*)d_in[1];
  const float* wq = (const float*)d_in[5];
  const float* bq = (const float*)d_in[6];
  const float* wk = (const float*)d_in[7];
  const float* bk = (const float*)d_in[8];
  const float* wv = (const float*)d_in[9];
  const float* bv = (const float*)d_in[10];
  const float* wo = (const float*)d_in[11];
  const float* bo = (const float*)d_in[12];
  const float* nq = (const float*)d_in[13];
  const float* nk = (const float*)d_in[14];
  const float* cf = (const float*)d_in[15];
  const float* sf = (const float*)d_in[16];
  const float* ch = (const float*)d_in[17];
  const float* sh = (const float*)d_in[18];
  const float* cw = (const float*)d_in[19];
  const float* sw = (const float*)d_in[20];

  const size_t rowelems = (size_t)M_ * DIM_;          // 6291456
  float* qf  = (float*)d_ws;
  float* kf  = qf + rowelems;
  float* vf  = kf + rowelems;
  short* x16 = (short*)(vf + rowelems);
  short* vt  = x16;                       // reuse after GEMMs
  short* qh  = (short*)vf;                // reuse after v_transpose
  short* kh  = qh + rowelems;
  short* att16 = (short*)qf;              // reuse after rms_rope(q)
  float* out = (float*)d_out;

  f2h_k<<<(int)(rowelems / 8 / 256), 256, 0, stream>>>(x, x16, (int)(rowelems / 8));

  gemm_qkv_k<<<dim3(DIM_ / 128, M_ / 128, 3), 256, 0, stream>>>(
      x16, wq, wk, wv, bq, bk, bv, qf, kf, vf);

  v_transpose_k<<<dim3(S_ / 64, B_ * NH_), 256, 0, stream>>>(vf, vt);

  rms_rope_pack_k<<<M_, 256, 0, stream>>>(qf, nq, cf, sf, ch, sh, cw, sw, qh,
                                          SSCALE_LOG2E);
  rms_rope_pack_k<<<M_, 256, 0, stream>>>(kf, nk, cf, sf, ch, sh, cw, sw, kh, 1.0f);

  attn_mfma5_k<<<dim3(S_ / 64, B_ * NH_), 256, 0, stream>>>(qh, kh, vt, seq_lens, att16);

  gemm_out_k<<<dim3(DIM_ / 128, M_ / 128), 256, 0, stream>>>(att16, wo, bo, out);
}

// Round 9
// 253.992 us; speedup vs baseline: 1.4639x; 1.0591x over previous
//
#include <hip/hip_runtime.h>
#include <hip/hip_bf16.h>
#include <math.h>

#define DIM_  1536
#define NH_   12
#define HD_   128
#define S_    2048
#define B_    2
#define M_    (B_*S_)   /* 4096 rows */
#define WEL_  (DIM_*DIM_)   /* 2359296 */

typedef __attribute__((ext_vector_type(8))) _Float16 f16x8;
typedef __attribute__((ext_vector_type(4))) short short4v;
typedef __attribute__((ext_vector_type(8))) short short8v;
typedef __attribute__((ext_vector_type(4))) float f32x4;

#define SSCALE_LOG2E (0.08838834764831845f * 1.4426950408889634f)

static __device__ __forceinline__ short f2h(float f) {
  union { _Float16 h; short s; } u;
  u.h = (_Float16)f;
  return u.s;
}

static __device__ __forceinline__ unsigned pk2h(float a, float b) {
  typedef __attribute__((ext_vector_type(2))) __fp16 fp16x2;
  union { fp16x2 v; unsigned u; } u2;
  u2.v = __builtin_amdgcn_cvt_pkrtz(a, b);
  return u2.u;
}

// ---------------------------------------------------------------------------
// fp32 -> fp16 pack, 8 elems/thread (generic)
// ---------------------------------------------------------------------------
__global__ __launch_bounds__(256) void f2h_k(
    const float* __restrict__ in, short* __restrict__ out, int n8)
{
  int i = blockIdx.x * 256 + threadIdx.x;
  if (i >= n8) return;
  const float4* p = (const float4*)in + (size_t)i * 2;
  float4 a = p[0], b = p[1];
  short8v o;
  o[0] = f2h(a.x); o[1] = f2h(a.y); o[2] = f2h(a.z); o[3] = f2h(a.w);
  o[4] = f2h(b.x); o[5] = f2h(b.y); o[6] = f2h(b.z); o[7] = f2h(b.w);
  *((short8v*)out + i) = o;
}

// ---------------------------------------------------------------------------
// Fused convert: x (786432 chunks) + wq/wk/wv (294912 chunks each) -> fp16.
// grid 6528 x 256 covers exactly 1671168 chunks.
// ---------------------------------------------------------------------------
__global__ __launch_bounds__(256) void f2h4_k(
    const float* __restrict__ x, const float* __restrict__ wq,
    const float* __restrict__ wk, const float* __restrict__ wv,
    short* __restrict__ x16, short* __restrict__ w16)
{
  int i = blockIdx.x * 256 + threadIdx.x;
  const float* src; short* dst; int j;
  if (i < 786432)       { src = x;  dst = x16;            j = i; }
  else if (i < 1081344) { src = wq; dst = w16;            j = i - 786432; }
  else if (i < 1376256) { src = wk; dst = w16 + WEL_;     j = i - 1081344; }
  else                  { src = wv; dst = w16 + 2 * WEL_; j = i - 1376256; }
  const float4* p = (const float4*)src + (size_t)j * 2;
  float4 a = p[0], b = p[1];
  short8v o;
  o[0] = f2h(a.x); o[1] = f2h(a.y); o[2] = f2h(a.z); o[3] = f2h(a.w);
  o[4] = f2h(b.x); o[5] = f2h(b.y); o[6] = f2h(b.z); o[7] = f2h(b.w);
  *((short8v*)dst + j) = o;
}

// ---------------------------------------------------------------------------
// MFMA fp16 GEMM core, both operands fp16 in global (m97 structure):
// Out[M,N] = A16[M,K] @ W16[N,K]^T + bias.  128x128 tile, BK=32, 4 waves.
// Both A and B staged via global_load_lds with pre-swizzled source
// (slot ^ ((row>>1)&3)); fragments read back with matching XOR.
// F16OUT: write fp16 (for V) instead of fp32.
// ---------------------------------------------------------------------------
template<bool F16OUT>
static __device__ __forceinline__ void gemm16_core(
    const short* __restrict__ A16, const short* __restrict__ W16,
    const float* __restrict__ bias, void* __restrict__ Outp,
    int m0, int n0)
{
  __shared__ __align__(16) char Atile[8192];
  __shared__ __align__(16) char Btile[8192];
  const int tid = threadIdx.x;
  const int l  = tid & 63, w = tid >> 6;
  const int wr = w >> 1, wc = w & 1;
  const int lc = l & 15, lg = l >> 4;

  f32x4 acc[4][4] = {};

  const int rs  = w * 16 + (l >> 2);                    // staging row (0..63)
  const int gsl = ((l & 3) ^ ((rs >> 1) & 3)) * 8;      // pre-swizzled slot
  const short* gA0 = A16 + (size_t)(m0 + rs) * DIM_ + gsl;
  const short* gA1 = A16 + (size_t)(m0 + 64 + rs) * DIM_ + gsl;
  const short* gB0 = W16 + (size_t)(n0 + rs) * DIM_ + gsl;
  const short* gB1 = W16 + (size_t)(n0 + 64 + rs) * DIM_ + gsl;

  for (int k0 = 0; k0 < DIM_; k0 += 32) {
    __builtin_amdgcn_global_load_lds(
        (const __attribute__((address_space(1))) unsigned*)(gA0 + k0),
        (__attribute__((address_space(3))) unsigned*)(Atile + w * 1024), 16, 0, 0);
    __builtin_amdgcn_global_load_lds(
        (const __attribute__((address_space(1))) unsigned*)(gA1 + k0),
        (__attribute__((address_space(3))) unsigned*)(Atile + 4096 + w * 1024), 16, 0, 0);
    __builtin_amdgcn_global_load_lds(
        (const __attribute__((address_space(1))) unsigned*)(gB0 + k0),
        (__attribute__((address_space(3))) unsigned*)(Btile + w * 1024), 16, 0, 0);
    __builtin_amdgcn_global_load_lds(
        (const __attribute__((address_space(1))) unsigned*)(gB1 + k0),
        (__attribute__((address_space(3))) unsigned*)(Btile + 4096 + w * 1024), 16, 0, 0);
    __syncthreads();

    f16x8 af[4], bf[4];
#pragma unroll
    for (int mt = 0; mt < 4; ++mt) {
      int ar = wr * 64 + mt * 16 + lc;
      af[mt] = *(const f16x8*)(Atile + ar * 64 + ((lg ^ ((ar >> 1) & 3)) << 4));
    }
#pragma unroll
    for (int nt = 0; nt < 4; ++nt) {
      int br = wc * 64 + nt * 16 + lc;
      bf[nt] = *(const f16x8*)(Btile + br * 64 + ((lg ^ ((br >> 1) & 3)) << 4));
    }
#pragma unroll
    for (int mt = 0; mt < 4; ++mt)
#pragma unroll
      for (int nt = 0; nt < 4; ++nt)
        acc[mt][nt] = __builtin_amdgcn_mfma_f32_16x16x32_f16(af[mt], bf[nt], acc[mt][nt], 0, 0, 0);
    __syncthreads();
  }

#pragma unroll
  for (int nt = 0; nt < 4; ++nt) {
    int col = n0 + wc * 64 + nt * 16 + lc;
    float bb = bias[col];
#pragma unroll
    for (int mt = 0; mt < 4; ++mt) {
#pragma unroll
      for (int r = 0; r < 4; ++r) {
        int rowm = m0 + wr * 64 + mt * 16 + lg * 4 + r;
        if (F16OUT)
          ((short*)Outp)[(size_t)rowm * DIM_ + col] = f2h(acc[mt][nt][r] + bb);
        else
          ((float*)Outp)[(size_t)rowm * DIM_ + col] = acc[mt][nt][r] + bb;
      }
    }
  }
}

__global__ __launch_bounds__(256) void gemm_qk_k(
    const short* __restrict__ x16, const short* __restrict__ w16,
    const float* __restrict__ bq, const float* __restrict__ bk,
    float* __restrict__ qf, float* __restrict__ kf)
{
  const int z = blockIdx.z;
  gemm16_core<false>(x16, w16 + (size_t)z * WEL_, z ? bk : bq,
                     z ? (void*)kf : (void*)qf,
                     blockIdx.y * 128, blockIdx.x * 128);
}

__global__ __launch_bounds__(256) void gemm_v16_k(
    const short* __restrict__ x16, const short* __restrict__ wv16,
    const float* __restrict__ bv, short* __restrict__ vf16)
{
  gemm16_core<true>(x16, wv16, bv, vf16, blockIdx.y * 128, blockIdx.x * 128);
}

__global__ __launch_bounds__(256) void gemm_out16_k(
    const short* __restrict__ att16, const short* __restrict__ wo16,
    const float* __restrict__ bo, float* __restrict__ out)
{
  gemm16_core<false>(att16, wo16, bo, out, blockIdx.y * 128, blockIdx.x * 128);
}

// ---------------------------------------------------------------------------
// RMSNorm + grid RoPE -> fp16 head-major [b][h][s][d], output scale folded in.
// ---------------------------------------------------------------------------
__global__ __launch_bounds__(256) void rms_rope_pack_k(
    const float* __restrict__ t, const float* __restrict__ w,
    const float* __restrict__ cf, const float* __restrict__ sf,
    const float* __restrict__ ch, const float* __restrict__ sh,
    const float* __restrict__ cw, const float* __restrict__ sw,
    short* __restrict__ outb, float qsc)
{
  const int row = blockIdx.x;
  const int b   = row >> 11;
  const int s   = row & (S_ - 1);
  const float* rp = t + (size_t)row * DIM_;

  float ss = 0.f;
  for (int i = threadIdx.x; i < DIM_; i += 256) { float v2 = rp[i]; ss += v2 * v2; }
#pragma unroll
  for (int off = 32; off > 0; off >>= 1) ss += __shfl_down(ss, off);
  __shared__ float red[4];
  if ((threadIdx.x & 63) == 0) red[threadIdx.x >> 6] = ss;
  __syncthreads();
  float scale = rsqrtf((red[0] + red[1] + red[2] + red[3]) * (1.f / DIM_) + 1e-6f) * qsc;

  const int fi = s >> 8;
  const int hi = (s >> 4) & 15;
  const int wi = s & 15;

  for (int p = threadIdx.x; p < NH_ * 64; p += 256) {
    int n = p >> 6, c = p & 63;
    float co, si;
    if (c < 22)      { co = cf[fi * 22 + c];        si = sf[fi * 22 + c]; }
    else if (c < 43) { co = ch[hi * 21 + (c - 22)]; si = sh[hi * 21 + (c - 22)]; }
    else             { co = cw[wi * 21 + (c - 43)]; si = sw[wi * 21 + (c - 43)]; }
    int d0 = n * HD_ + 2 * c;
    float xr = rp[d0]     * scale * w[d0];
    float xi = rp[d0 + 1] * scale * w[d0 + 1];
    float rr = xr * co - xi * si;
    float ri = xr * si + xi * co;
    *(unsigned int*)(outb + (((size_t)(b * NH_ + n) * S_ + s) * HD_ + 2 * c)) = pk2h(rr, ri);
  }
}

// ---------------------------------------------------------------------------
// V transpose: fp16 [b*S+s][h*128+d] -> fp16 [b][h][d][s]
// ---------------------------------------------------------------------------
__global__ __launch_bounds__(256) void v_transpose16_k(
    const short* __restrict__ v16, short* __restrict__ vtb)
{
  const int bh = blockIdx.y;
  const int b  = bh / NH_;
  const int h  = bh - b * NH_;
  const int s0 = blockIdx.x << 6;
  __shared__ short tile[64][136];
  const int tid = threadIdx.x;
#pragma unroll
  for (int i = 0; i < 4; ++i) {
    int f  = tid + (i << 8);            // 0..1023
    int sl = f >> 4, d8 = f & 15;
    short8v v8 = *(const short8v*)(v16 + (size_t)(b * S_ + s0 + sl) * DIM_ + h * 128 + d8 * 8);
#pragma unroll
    for (int j = 0; j < 8; ++j) tile[sl][d8 * 8 + j] = v8[j];
  }
  __syncthreads();
#pragma unroll
  for (int i = 0; i < 4; ++i) {
    int f  = tid + (i << 8);
    int d  = f >> 3, s8 = f & 7;
    short8v o8;
#pragma unroll
    for (int j = 0; j < 8; ++j) o8[j] = tile[s8 * 8 + j][d];
    *(short8v*)(vtb + ((size_t)bh * HD_ + d) * S_ + s0 + s8 * 8) = o8;
  }
}

// ---------------------------------------------------------------------------
// fp16 MFMA flash attention v5 (unchanged from R7): 4 waves x 16 queries,
// LDS-shared K/V, split-barrier pipeline, in-lane log2-domain softmax,
// defer-max, hoisted pre-swizzled global_load_lds staging.
// ---------------------------------------------------------------------------
__global__ __launch_bounds__(256) void attn_mfma5_k(
    const short* __restrict__ qb, const short* __restrict__ kb,
    const short* __restrict__ vtb, const int* __restrict__ seq_lens,
    short* __restrict__ o16)
{
  const int bh = blockIdx.y;
  const int b  = bh / NH_;
  const int h  = bh - b * NH_;
  const int q0 = blockIdx.x << 6;
  const int kvlen = seq_lens[b];
  const int tid  = threadIdx.x;
  const int wid  = tid >> 6;
  const int lane = tid & 63;
  const int lg   = lane >> 4;
  const int lc   = lane & 15;
  const int xo   = (lc & 7) << 4;

  __shared__ __align__(16) char Kt[16384];
  __shared__ __align__(16) char Vt[16384];
  __shared__ __align__(16) char Pt[4][2048];

  f16x8 bq[4];
  {
    const size_t base = ((size_t)bh * S_ + q0 + wid * 16 + lc) * HD_;
#pragma unroll
    for (int dc = 0; dc < 4; ++dc)
      bq[dc] = *(const f16x8*)(qb + base + dc * 32 + lg * 8);
  }

  const short* kgA = kb + ((size_t)bh * S_ + wid * 16 + lg) * HD_
                        + ((lc * 8) ^ (lg << 3));
  const short* kgB = kb + ((size_t)bh * S_ + wid * 16 + 4 + lg) * HD_
                        + ((lc * 8) ^ ((lg ^ 4) << 3));
  const short* vg  = vtb + ((size_t)bh * HD_ + wid * 32 + (lane >> 3)) * S_
                         + (((lane & 7) * 8) ^ ((lane >> 3) << 3));

#define STAGE_K()                                                              \
  {                                                                            \
    _Pragma("unroll")                                                          \
    for (int j = 0; j < 4; ++j) {                                              \
      const short* g = (j & 1) ? (kgB + ((j - 1) >> 1) * (8 * HD_))            \
                               : (kgA + (j >> 1) * (8 * HD_));                 \
      __builtin_amdgcn_global_load_lds(                                        \
          (const __attribute__((address_space(1))) unsigned*)g,                \
          (__attribute__((address_space(3))) unsigned*)(Kt + (wid * 16 + j * 4) * 256), \
          16, 0, 0);                                                           \
    }                                                                          \
  }
#define STAGE_V()                                                              \
  {                                                                            \
    _Pragma("unroll")                                                          \
    for (int j = 0; j < 4; ++j) {                                              \
      __builtin_amdgcn_global_load_lds(                                        \
          (const __attribute__((address_space(1))) unsigned*)(vg + j * 8 * S_),\
          (__attribute__((address_space(3))) unsigned*)(Vt + (wid * 32 + j * 8) * 128), \
          16, 0, 0);                                                           \
    }                                                                          \
  }

  f32x4 oacc[8] = {};
  float m = -3.0e38f, l = 0.f;

  const int nt = kvlen >> 6;

  STAGE_K();
  kgA += 64 * HD_; kgB += 64 * HD_;
  __syncthreads();

  for (int ti = 0; ti < nt; ++ti) {
    STAGE_V();
    vg += 64;

    f32x4 s[4];
    __builtin_amdgcn_s_setprio(1);
#pragma unroll
    for (int kt = 0; kt < 4; ++kt) {
      f32x4 a = {0.f, 0.f, 0.f, 0.f};
      const char* kr = Kt + (kt * 16 + lc) * 256;
#pragma unroll
      for (int dc = 0; dc < 4; ++dc) {
        f16x8 kf = *(const f16x8*)(kr + ((dc * 64 + lg * 16) ^ xo));
        a = __builtin_amdgcn_mfma_f32_16x16x32_f16(kf, bq[dc], a, 0, 0, 0);
      }
      s[kt] = a;
    }
    __builtin_amdgcn_s_setprio(0);

    float t0 = -3.0e38f;
#pragma unroll
    for (int kt = 0; kt < 4; ++kt)
#pragma unroll
      for (int r = 0; r < 4; ++r) t0 = fmaxf(t0, s[kt][r]);
    t0 = fmaxf(t0, __shfl_xor(t0, 16));
    t0 = fmaxf(t0, __shfl_xor(t0, 32));

    if (__any(t0 > m + 8.f)) {
      float mn = fmaxf(m, t0);
      float a  = exp2f(m - mn);
      m = mn; l *= a;
#pragma unroll
      for (int r = 0; r < 4; ++r) {
        float ar = __shfl(a, 4 * lg + r);
#pragma unroll
        for (int n = 0; n < 8; ++n) oacc[n][r] *= ar;
      }
    }
    float ls = 0.f;
#pragma unroll
    for (int kt = 0; kt < 4; ++kt)
#pragma unroll
      for (int r = 0; r < 4; ++r) {
        float p = exp2f(s[kt][r] - m); s[kt][r] = p; ls += p;
      }
    ls += __shfl_xor(ls, 16);
    ls += __shfl_xor(ls, 32);
    l += ls;

    {
      char* pr = Pt[wid] + lc * 128;
#pragma unroll
      for (int kt = 0; kt < 4; ++kt) {
#pragma unroll
        for (int rr = 0; rr < 2; ++rr) {
          unsigned u = pk2h(s[kt][2 * rr], s[kt][2 * rr + 1]);
          int off = (kt * 32 + lg * 8 + rr * 4) ^ xo;
          *(unsigned*)(pr + off) = u;
        }
      }
    }

    __syncthreads();

    if (ti + 1 < nt) {
      STAGE_K();
      kgA += 64 * HD_; kgB += 64 * HD_;
    }

    __builtin_amdgcn_s_setprio(1);
#pragma unroll
    for (int kc = 0; kc < 2; ++kc) {
      f16x8 pa = *(const f16x8*)(Pt[wid] + lc * 128 + ((kc * 64 + lg * 16) ^ xo));
#pragma unroll
      for (int n = 0; n < 8; ++n) {
        f16x8 vf = *(const f16x8*)(Vt + (n * 16 + lc) * 128 + ((kc * 64 + lg * 16) ^ xo));
        oacc[n] = __builtin_amdgcn_mfma_f32_16x16x32_f16(pa, vf, oacc[n], 0, 0, 0);
      }
    }
    __builtin_amdgcn_s_setprio(0);

    __syncthreads();
  }

#pragma unroll
  for (int r = 0; r < 4; ++r) {
    float li = 1.f / __shfl(l, 4 * lg + r);
    int qrow = q0 + wid * 16 + 4 * lg + r;
#pragma unroll
    for (int n = 0; n < 8; ++n)
      o16[((size_t)(b * S_ + qrow) * NH_ + h) * HD_ + n * 16 + lc] = f2h(oacc[n][r] * li);
  }
#undef STAGE_K
#undef STAGE_V
}

// ---------------------------------------------------------------------------
// Workspace plan (89.7 MB):
//  A [0, 25.17M):      qf fp32        -> att16 (lower 12.58M) + kh (upper 12.58M)
//  B [25.17M, 50.34M): kf fp32        -> wo16 (4.72M) after rms_rope(k)
//  C [50.34M, 62.93M): vf16           -> qh after v_transpose
//  D [62.93M, 75.51M): x16            -> vt after qkv GEMMs
//  E [75.51M, 89.67M): wq16|wk16|wv16
// ---------------------------------------------------------------------------
extern "C" void kernel_launch(void* const* d_in, const int* in_sizes, int n_in,
                              void* d_out, int out_size, void* d_ws, size_t ws_size,
                              hipStream_t stream) {
  const float* x        = (const float*)d_in[0];
  const int*   seq_lens = (const int*)d_in[1];
  const float* wq = (const float*)d_in[5];
  const float* bq = (const float*)d_in[6];
  const float* wk = (const float*)d_in[7];
  const float* bk = (const float*)d_in[8];
  const float* wv = (const float*)d_in[9];
  const float* bv = (const float*)d_in[10];
  const float* wo = (const float*)d_in[11];
  const float* bo = (const float*)d_in[12];
  const float* nq = (const float*)d_in[13];
  const float* nk = (const float*)d_in[14];
  const float* cf = (const float*)d_in[15];
  const float* sf = (const float*)d_in[16];
  const float* ch = (const float*)d_in[17];
  const float* sh = (const float*)d_in[18];
  const float* cw = (const float*)d_in[19];
  const float* sw = (const float*)d_in[20];

  const size_t rowelems = (size_t)M_ * DIM_;          // 6291456
  float* qf   = (float*)d_ws;
  float* kf   = qf + rowelems;
  short* vf16 = (short*)(kf + rowelems);
  short* x16  = vf16 + rowelems;
  short* w16  = x16 + rowelems;                       // wq16|wk16|wv16
  short* vt   = x16;                                  // after qkv GEMMs
  short* qh   = vf16;                                 // after v_transpose
  short* kh   = (short*)d_ws + rowelems;              // A upper half
  short* att16 = (short*)d_ws;                        // A lower half
  short* wo16 = (short*)kf;                           // B region after rms_rope(k)
  float* out  = (float*)d_out;

  f2h4_k<<<6528, 256, 0, stream>>>(x, wq, wk, wv, x16, w16);

  gemm_qk_k<<<dim3(DIM_ / 128, M_ / 128, 2), 256, 0, stream>>>(
      x16, w16, bq, bk, qf, kf);
  gemm_v16_k<<<dim3(DIM_ / 128, M_ / 128), 256, 0, stream>>>(
      x16, w16 + 2 * (size_t)WEL_, bv, vf16);

  v_transpose16_k<<<dim3(S_ / 64, B_ * NH_), 256, 0, stream>>>(vf16, vt);

  rms_rope_pack_k<<<M_, 256, 0, stream>>>(qf, nq, cf, sf, ch, sh, cw, sw, qh,
                                          SSCALE_LOG2E);
  rms_rope_pack_k<<<M_, 256, 0, stream>>>(kf, nk, cf, sf, ch, sh, cw, sw, kh, 1.0f);

  f2h_k<<<1152, 256, 0, stream>>>(wo, wo16, WEL_ / 8);

  attn_mfma5_k<<<dim3(S_ / 64, B_ * NH_), 256, 0, stream>>>(qh, kh, vt, seq_lens, att16);

  gemm_out16_k<<<dim3(DIM_ / 128, M_ / 128), 256, 0, stream>>>(att16, wo16, bo, out);
}